// Round 1
// baseline (390.951 us; speedup 1.0000x reference)
//
#include <hip/hip_runtime.h>

// NGNNConv: out[i,j,:] = mask[i,j] * sum_{e: erow[e]==j} mask[i,ecol[e]] * (X[i,ecol[e],:] @ W + b)
// N=1024 nodes, E=8192 edges, IND=OUTD=32, fp32.
// Strategy: aggregate-then-GEMM (W applied once per output row), fused in one kernel.

#define NN   1024
#define NE   8192
#define IND  32
#define OUTD 32
#define TI   64      // i-rows per block
#define SROW 36      // padded LDS row stride in floats (144B, 16B-aligned, conflict-free b128 reads)

// ---------------- CSR build: bucket edges by destination row j ----------------
__global__ __launch_bounds__(1024) void build_csr_kernel(
    const int* __restrict__ erow, const int* __restrict__ ecol,
    int* __restrict__ row_ptr, int* __restrict__ cols, int n_edges)
{
    __shared__ int cnt[NN];
    __shared__ int scan_buf[NN];
    const int t = threadIdx.x;
    cnt[t] = 0;
    __syncthreads();
    for (int e = t; e < n_edges; e += 1024) atomicAdd(&cnt[erow[e]], 1);
    __syncthreads();
    const int v = cnt[t];
    scan_buf[t] = v;
    __syncthreads();
    // Hillis-Steele inclusive scan over 1024 elements
    for (int off = 1; off < NN; off <<= 1) {
        int add = (t >= off) ? scan_buf[t - off] : 0;
        __syncthreads();
        scan_buf[t] += add;
        __syncthreads();
    }
    const int excl = scan_buf[t] - v;   // exclusive prefix
    row_ptr[t] = excl;
    if (t == NN - 1) row_ptr[NN] = scan_buf[t];
    cnt[t] = excl;                      // running fill offsets
    __syncthreads();
    for (int e = t; e < n_edges; e += 1024) {
        const int pos = atomicAdd(&cnt[erow[e]], 1);
        cols[pos] = ecol[e];
    }
}

// ---------------- Fused gather + GEMM ----------------
// grid = (NN/TI, NN): blockIdx.x = i-tile, blockIdx.y = j. block = 256 threads.
// thread: c4 = tid&7 (float4 channel group), slot = tid>>3 (0..31); owns i = i0+slot and i0+slot+32.
__global__ __launch_bounds__(256) void ngnn_main_kernel(
    const float* __restrict__ X, const int* __restrict__ mask,
    const float* __restrict__ W, const float* __restrict__ b,
    const int* __restrict__ row_ptr, const int* __restrict__ cols,
    float* __restrict__ out)
{
    __shared__ float Sl[TI * SROW];      // aggregated S tile, padded rows
    __shared__ float Wl[IND * OUTD];     // W staged
    __shared__ float Cl[TI];             // masked edge count per row (for the b term)
    __shared__ int   Kl[256];            // staged source-col chunk

    const int tid  = threadIdx.x;
    const int c4   = tid & 7;
    const int slot = tid >> 3;
    const int j    = blockIdx.y;
    const int i0   = blockIdx.x * TI;

    // stage W: 256 threads x float4 = 1024 floats
    ((float4*)Wl)[tid] = ((const float4*)W)[tid];

    const int ia = i0 + slot;
    const int ib = i0 + slot + 32;
    const int mja = mask[(size_t)ia * NN + j];
    const int mjb = mask[(size_t)ib * NN + j];

    float4 sa = {0.f, 0.f, 0.f, 0.f};
    float4 sb = {0.f, 0.f, 0.f, 0.f};
    float  ca = 0.f, cb = 0.f;

    const int e0 = row_ptr[j];
    const int e1 = row_ptr[j + 1];
    for (int base = e0; base < e1; base += 256) {
        const int chunk = min(256, e1 - base);
        if (tid < chunk) Kl[tid] = cols[base + tid];
        __syncthreads();
        for (int c = 0; c < chunk; ++c) {
            const int k = Kl[c];
            if (mja) {
                const int mk = mask[(size_t)ia * NN + k];
                if (mk) {
                    const float4 x = ((const float4*)(X + ((size_t)ia * NN + k) * IND))[c4];
                    sa.x += x.x; sa.y += x.y; sa.z += x.z; sa.w += x.w;
                    ca += 1.f;
                }
            }
            if (mjb) {
                const int mk = mask[(size_t)ib * NN + k];
                if (mk) {
                    const float4 x = ((const float4*)(X + ((size_t)ib * NN + k) * IND))[c4];
                    sb.x += x.x; sb.y += x.y; sb.z += x.z; sb.w += x.w;
                    cb += 1.f;
                }
            }
        }
        __syncthreads();   // protect Kl before next chunk overwrites it
    }

    // write S tile (zeros if masked-out or no edges -> output becomes exactly 0)
    ((float4*)(Sl + slot * SROW))[c4]        = sa;
    ((float4*)(Sl + (ib - i0) * SROW))[c4]   = sb;
    if (c4 == 0) { Cl[slot] = ca; Cl[slot + 32] = cb; }
    __syncthreads();

    // ---------------- phase 2: out[i, j, c] = S[i,:] @ W[:, c] + b[c]*cnt[i] ----------------
    const float4 bv = ((const float4*)b)[c4];
    const float cA = Cl[slot];
    const float cB = Cl[slot + 32];
    float4 oa = { bv.x * cA, bv.y * cA, bv.z * cA, bv.w * cA };
    float4 ob = { bv.x * cB, bv.y * cB, bv.z * cB, bv.w * cB };

    const float* SrA = Sl + slot * SROW;
    const float* SrB = Sl + (slot + 32) * SROW;
    #pragma unroll
    for (int d4 = 0; d4 < 8; ++d4) {
        const float4 w0 = ((const float4*)(Wl + (d4 * 4 + 0) * OUTD))[c4];
        const float4 w1 = ((const float4*)(Wl + (d4 * 4 + 1) * OUTD))[c4];
        const float4 w2 = ((const float4*)(Wl + (d4 * 4 + 2) * OUTD))[c4];
        const float4 w3 = ((const float4*)(Wl + (d4 * 4 + 3) * OUTD))[c4];
        const float4 s  = ((const float4*)SrA)[d4];
        const float4 t  = ((const float4*)SrB)[d4];

        oa.x += s.x * w0.x + s.y * w1.x + s.z * w2.x + s.w * w3.x;
        oa.y += s.x * w0.y + s.y * w1.y + s.z * w2.y + s.w * w3.y;
        oa.z += s.x * w0.z + s.y * w1.z + s.z * w2.z + s.w * w3.z;
        oa.w += s.x * w0.w + s.y * w1.w + s.z * w2.w + s.w * w3.w;

        ob.x += t.x * w0.x + t.y * w1.x + t.z * w2.x + t.w * w3.x;
        ob.y += t.x * w0.y + t.y * w1.y + t.z * w2.y + t.w * w3.y;
        ob.z += t.x * w0.z + t.y * w1.z + t.z * w2.z + t.w * w3.z;
        ob.w += t.x * w0.w + t.y * w1.w + t.z * w2.w + t.w * w3.w;
    }

    ((float4*)(out + ((size_t)ia * NN + j) * OUTD))[c4] = oa;
    ((float4*)(out + ((size_t)ib * NN + j) * OUTD))[c4] = ob;
}

extern "C" void kernel_launch(void* const* d_in, const int* in_sizes, int n_in,
                              void* d_out, int out_size, void* d_ws, size_t ws_size,
                              hipStream_t stream) {
    const float* X    = (const float*)d_in[0];
    const int*   mask = (const int*)d_in[1];
    const int*   erow = (const int*)d_in[2];
    const int*   ecol = (const int*)d_in[3];
    const float* W    = (const float*)d_in[4];
    const float* b    = (const float*)d_in[5];
    float*       out  = (float*)d_out;

    const int n_edges = in_sizes[2];

    // ws layout: row_ptr [0 .. 1024] ints, cols at int offset 2048
    int* row_ptr = (int*)d_ws;
    int* cols    = (int*)d_ws + 2048;

    build_csr_kernel<<<1, 1024, 0, stream>>>(erow, ecol, row_ptr, cols, n_edges);

    dim3 grid(NN / TI, NN);
    ngnn_main_kernel<<<grid, 256, 0, stream>>>(X, mask, W, b, row_ptr, cols, out);
}

// Round 2
// 309.670 us; speedup vs baseline: 1.2625x; 1.2625x over previous
//
#include <hip/hip_runtime.h>

// NGNNConv: out[i,j,:] = m[i,j] * [ (sum_{e: erow[e]=j} m[i,ecol[e]] * X[i,ecol[e],:]) @ W + b * cnt ]
// N=1024, E=8192, IND=OUTD=32, fp32.
//
// R2 design: block-per-i. X[i,:,:] (128 KB) streamed coalesced into LDS once
// (compulsory 134 MB total instead of ~557 MB of random global gathers),
// edge gather served from LDS, S kept in registers, W via scalar loads.
// LDS rows are segment-XOR-swizzled (p = seg ^ (k&7)) so random-row b128
// gathers spread over all 32 banks instead of concentrating on 4.

#define NN   1024
#define IND  32
#define OUTD 32

// ---------------- CSR build (parallel, 4 tiny kernels) ----------------
__global__ __launch_bounds__(1024) void k_zero(int* __restrict__ p, int n) {
    const int t = blockIdx.x * 1024 + threadIdx.x;
    if (t < n) p[t] = 0;
}

__global__ __launch_bounds__(1024) void k_count(const int* __restrict__ erow,
                                                int* __restrict__ cnt, int n_edges) {
    const int e = blockIdx.x * 1024 + threadIdx.x;
    if (e < n_edges) atomicAdd(&cnt[erow[e]], 1);
}

__global__ __launch_bounds__(1024) void k_scan(const int* __restrict__ cnt,
                                               int* __restrict__ row_ptr,
                                               int* __restrict__ fill) {
    __shared__ int sb[NN];
    const int t = threadIdx.x;
    const int v = cnt[t];
    sb[t] = v;
    __syncthreads();
    #pragma unroll
    for (int off = 1; off < NN; off <<= 1) {
        const int a = (t >= off) ? sb[t - off] : 0;
        __syncthreads();
        sb[t] += a;
        __syncthreads();
    }
    const int excl = sb[t] - v;
    row_ptr[t] = excl;
    fill[t]    = excl;
    if (t == NN - 1) row_ptr[NN] = sb[t];
}

__global__ __launch_bounds__(1024) void k_scatter(const int* __restrict__ erow,
                                                  const int* __restrict__ ecol,
                                                  int* __restrict__ fill,
                                                  int* __restrict__ cols, int n_edges) {
    const int e = blockIdx.x * 1024 + threadIdx.x;
    if (e < n_edges) {
        const int pos = atomicAdd(&fill[erow[e]], 1);
        cols[pos] = ecol[e];
    }
}

// ---------------- main: block per i ----------------
__global__ __launch_bounds__(1024) void ngnn_main_kernel(
    const float* __restrict__ X, const int* __restrict__ mask,
    const float* __restrict__ W, const float* __restrict__ b,
    const int* __restrict__ row_ptr, const int* __restrict__ cols,
    float* __restrict__ out)
{
    extern __shared__ float smem[];
    float* Xl    = smem;                       // 1024*32 floats, seg-swizzled (128 KB)
    int*   maskl = (int*)(smem + NN * IND);    // 1024 ints (4 KB)

    const int t = threadIdx.x;
    const int i = blockIdx.x;

    maskl[t] = mask[(size_t)i * NN + t];

    // Phase 1: coalesced stream of X[i,:,:] into LDS, XOR-swizzled segments.
    const float4* Xg = (const float4*)(X + (size_t)i * NN * IND);
    #pragma unroll
    for (int it = 0; it < 8; ++it) {
        const int f4 = it * 1024 + t;          // float4 index within the 128 KB slab
        const float4 v = Xg[f4];
        const int k = f4 >> 3;                 // row (8 float4 per 32-float row)
        const int p = (f4 & 7) ^ (k & 7);      // swizzled segment slot
        *(float4*)(Xl + k * IND + (p << 2)) = v;
    }
    __syncthreads();

    // Phase 2: thread j = t. Aggregate masked edge-source rows from LDS.
    const int j = t;
    float4* orow = (float4*)(out + ((size_t)i * NN + j) * OUTD);

    if (maskl[j] == 0) {                       // output gated to exact zero
        const float4 z = {0.f, 0.f, 0.f, 0.f};
        #pragma unroll
        for (int q = 0; q < 8; ++q) orow[q] = z;
        return;
    }

    float S[IND];
    #pragma unroll
    for (int d = 0; d < IND; ++d) S[d] = 0.f;
    float cntf = 0.f;

    const int e0 = row_ptr[j];
    const int e1 = row_ptr[j + 1];
    for (int e = e0; e < e1; ++e) {
        const int k = cols[e];
        if (maskl[k]) {
            cntf += 1.f;
            const float* rb = Xl + k * IND;
            const int kb = k & 7;
            #pragma unroll
            for (int s = 0; s < 8; ++s) {      // read logical seg s from slot s^kb
                const float4 v = *(const float4*)(rb + (((s ^ kb) << 2)));
                S[s * 4 + 0] += v.x;
                S[s * 4 + 1] += v.y;
                S[s * 4 + 2] += v.z;
                S[s * 4 + 3] += v.w;
            }
        }
    }

    // Phase 3: o[c] = S . W[:,c] + b[c]*cnt. W/b indices are wave-uniform -> s_load.
    float o[OUTD];
    #pragma unroll
    for (int c = 0; c < OUTD; ++c) o[c] = b[c] * cntf;
    #pragma unroll
    for (int d = 0; d < IND; ++d) {
        const float s = S[d];
        #pragma unroll
        for (int c = 0; c < OUTD; ++c) o[c] += s * W[d * OUTD + c];
    }

    #pragma unroll
    for (int q = 0; q < 8; ++q) {
        const float4 ov = { o[q*4+0], o[q*4+1], o[q*4+2], o[q*4+3] };
        orow[q] = ov;
    }
}

extern "C" void kernel_launch(void* const* d_in, const int* in_sizes, int n_in,
                              void* d_out, int out_size, void* d_ws, size_t ws_size,
                              hipStream_t stream) {
    const float* X    = (const float*)d_in[0];
    const int*   mask = (const int*)d_in[1];
    const int*   erow = (const int*)d_in[2];
    const int*   ecol = (const int*)d_in[3];
    const float* W    = (const float*)d_in[4];
    const float* b    = (const float*)d_in[5];
    float*       out  = (float*)d_out;

    const int n_edges = in_sizes[2];

    // ws layout (ints): cnt[1024] | row_ptr[1025] @1024 | fill[1024] @2560 | cols @4096
    int* cnt     = (int*)d_ws;
    int* row_ptr = cnt + 1024;
    int* fill    = cnt + 2560;
    int* cols    = cnt + 4096;

    const int eb = (n_edges + 1023) / 1024;
    k_zero   <<<1, 1024, 0, stream>>>(cnt, NN);
    k_count  <<<eb, 1024, 0, stream>>>(erow, cnt, n_edges);
    k_scan   <<<1, 1024, 0, stream>>>(cnt, row_ptr, fill);
    k_scatter<<<eb, 1024, 0, stream>>>(erow, ecol, fill, cols, n_edges);

    const size_t shmem = (size_t)NN * IND * sizeof(float) + NN * sizeof(int); // 132 KB
    hipFuncSetAttribute((const void*)ngnn_main_kernel,
                        hipFuncAttributeMaxDynamicSharedMemorySize, (int)shmem);
    ngnn_main_kernel<<<NN, 1024, shmem, stream>>>(X, mask, W, b, row_ptr, cols, out);
}